// Round 4
// baseline (452.734 us; speedup 1.0000x reference)
//
#include <hip/hip_runtime.h>
#include <hip/hip_bf16.h>
#include <stdint.h>

typedef unsigned short u16;
typedef __attribute__((ext_vector_type(4))) float f32x4;
typedef __attribute__((ext_vector_type(8))) short bf16x8;
typedef __attribute__((ext_vector_type(4))) short bf16x4;
typedef __attribute__((ext_vector_type(4))) unsigned short u16x4;

static __device__ __forceinline__ u16 f2bf(float f) {
    union { float f; unsigned u; } v; v.f = f;
    unsigned r = v.u + 0x7fffu + ((v.u >> 16) & 1u);
    return (u16)(r >> 16);
}

// async global->LDS, 16B per lane; LDS dest = wave-uniform base + lane*16
static __device__ __forceinline__ void gload_lds16(const u16* g, u16* l) {
    __builtin_amdgcn_global_load_lds(
        (const __attribute__((address_space(1))) void*)(uintptr_t)g,
        (__attribute__((address_space(3))) void*)(uint32_t)(uintptr_t)l,
        16, 0, 0);
}

// ---------------- weight transpose + cast: out[n*K+k] = (bf16) W[k*N+n] ---------------
__global__ __launch_bounds__(256) void transpose_cast_b(
    const float* __restrict__ W, u16* __restrict__ out,
    int K, int N, long in_bs, long out_bs)
{
    __shared__ float tile[32][33];
    const float* Wb = W + (size_t)blockIdx.z * in_bs;
    u16* ob = out + (size_t)blockIdx.z * out_bs;
    int nt = blockIdx.x * 32, kt = blockIdx.y * 32;
    int tx = threadIdx.x & 31, ty = threadIdx.x >> 5;
    #pragma unroll
    for (int i = ty; i < 32; i += 8)
        tile[i][tx] = Wb[(size_t)(kt + i) * N + nt + tx];
    __syncthreads();
    #pragma unroll
    for (int i = ty; i < 32; i += 8)
        ob[(size_t)(nt + i) * K + kt + tx] = f2bf(tile[tx][i]);
}

// ---------------- layernorm: fp32 in -> bf16 out (D = 1024) ---------------
__global__ __launch_bounds__(256) void ln_kernel(
    const float* __restrict__ x, const float* __restrict__ g,
    const float* __restrict__ be, u16* __restrict__ out)
{
    int row = blockIdx.x;
    int t = threadIdx.x;
    const float4* xr = (const float4*)(x + (size_t)row * 1024);
    float4 v = xr[t];
    float s = v.x + v.y + v.z + v.w;
    float sq = v.x * v.x + v.y * v.y + v.z * v.z + v.w * v.w;
    #pragma unroll
    for (int o = 1; o < 64; o <<= 1) {
        s  += __shfl_xor(s, o);
        sq += __shfl_xor(sq, o);
    }
    __shared__ float ps[4], pq[4];
    if ((t & 63) == 0) { ps[t >> 6] = s; pq[t >> 6] = sq; }
    __syncthreads();
    float S = ps[0] + ps[1] + ps[2] + ps[3];
    float Q = pq[0] + pq[1] + pq[2] + pq[3];
    float mu = S * (1.0f / 1024.0f);
    float var = Q * (1.0f / 1024.0f) - mu * mu;
    float rs = rsqrtf(var + 1e-5f);
    const float4 g4  = ((const float4*)g)[t];
    const float4 be4 = ((const float4*)be)[t];
    u16x4 o4;
    o4[0] = f2bf((v.x - mu) * rs * g4.x + be4.x);
    o4[1] = f2bf((v.y - mu) * rs * g4.y + be4.y);
    o4[2] = f2bf((v.z - mu) * rs * g4.z + be4.z);
    o4[3] = f2bf((v.w - mu) * rs * g4.w + be4.w);
    *(u16x4*)(out + (size_t)row * 1024 + t * 4) = o4;
}

// ---------------- GEMM 128x128: C = A[M,K] * Bt[N,K]^T -------------------------------
// EPI 2: gelu(C + bias[n]) -> bf16 to Cout.
// EPI 3: qkv projection scatter: col<1024 -> Q buf [4096][1024] bf16;
//        1024..2047 -> Kp[bh][p][64]; 2048..3071 -> Vt[bh][64][p].
template<int EPI>
__global__ __launch_bounds__(256) void gemm_bt(
    const u16* __restrict__ A, const u16* __restrict__ Bt,
    int M, int N, int K,
    const float* __restrict__ bias,
    void* __restrict__ Cout, u16* __restrict__ Kp, u16* __restrict__ Vt)
{
    __shared__ __align__(16) u16 As[128 * 32];
    __shared__ __align__(16) u16 Bs[128 * 32];
    const int tm = blockIdx.y * 128, tn = blockIdx.x * 128;
    const int t = threadIdx.x;
    const int lane = t & 63, wave = t >> 6;
    const int wr = wave >> 1, wc = wave & 1;
    const int lq = lane & 15, lg = lane >> 4;
    f32x4 acc[4][4] = {};
    const int srow = wave * 32 + (lane >> 2);
    const int scol = (lane & 3) * 8;
    const u16* ag = A  + (size_t)(tm + srow) * K + scol;
    const u16* bg = Bt + (size_t)(tn + srow) * K + scol;
    u16* asl = As + wave * 1024;
    u16* bsl = Bs + wave * 1024;
    const size_t rowskip = (size_t)16 * K;
    for (int k0 = 0; k0 < K; k0 += 32) {
        gload_lds16(ag + k0,           asl);
        gload_lds16(ag + k0 + rowskip, asl + 512);
        gload_lds16(bg + k0,           bsl);
        gload_lds16(bg + k0 + rowskip, bsl + 512);
        __syncthreads();
        bf16x8 af[4], bfr[4];
        #pragma unroll
        for (int m = 0; m < 4; ++m)
            af[m] = *(const bf16x8*)(As + (wr * 64 + m * 16 + lq) * 32 + lg * 8);
        #pragma unroll
        for (int n = 0; n < 4; ++n)
            bfr[n] = *(const bf16x8*)(Bs + (wc * 64 + n * 16 + lq) * 32 + lg * 8);
        #pragma unroll
        for (int m = 0; m < 4; ++m)
            #pragma unroll
            for (int n = 0; n < 4; ++n)
                acc[m][n] = __builtin_amdgcn_mfma_f32_16x16x32_bf16(af[m], bfr[n], acc[m][n], 0, 0, 0);
        __syncthreads();
    }
    #pragma unroll
    for (int n = 0; n < 4; ++n) {
        const int colbase = tn + wc * 64 + n * 16;
        const int col = colbase + lq;
        #pragma unroll
        for (int m = 0; m < 4; ++m) {
            const int row0 = tm + wr * 64 + m * 16 + lg * 4;
            if (EPI == 2) {
                #pragma unroll
                for (int r = 0; r < 4; ++r) {
                    float xx = acc[m][n][r] + bias[col];
                    float ge = 0.5f * xx * (1.0f + erff(xx * 0.70710678118654752f));
                    ((u16*)Cout)[(size_t)(row0 + r) * N + col] = f2bf(ge);
                }
            } else { // EPI == 3
                const int bb = row0 >> 11, pp = row0 & 2047;
                if (colbase < 1024) {
                    #pragma unroll
                    for (int r = 0; r < 4; ++r)
                        ((u16*)Cout)[(size_t)(row0 + r) * 1024 + col] = f2bf(acc[m][n][r]);
                } else if (colbase < 2048) {
                    const int hh = (colbase - 1024) >> 6;
                    const int d = col & 63;
                    u16* kd = Kp + ((size_t)(bb * 16 + hh) * 2048 + pp) * 64 + d;
                    #pragma unroll
                    for (int r = 0; r < 4; ++r)
                        kd[r * 64] = f2bf(acc[m][n][r]);
                } else {
                    const int hh = (colbase - 2048) >> 6;
                    const int d = col & 63;
                    u16x4 pk;
                    #pragma unroll
                    for (int r = 0; r < 4; ++r) pk[r] = f2bf(acc[m][n][r]);
                    *(u16x4*)(Vt + ((size_t)(bb * 16 + hh) * 64 + d) * 2048 + pp) = pk;
                }
            }
        }
    }
}

// ---------------- GEMM 128x64 tile (for N=1024 shapes, 2 blocks/CU) ------------------
// out fp32: C + bias[n] + res[m,n]
__global__ __launch_bounds__(256) void gemm_bt64(
    const u16* __restrict__ A, const u16* __restrict__ Bt,
    int M, int N, int K,
    const float* __restrict__ bias, const float* __restrict__ res,
    float* __restrict__ Cout)
{
    __shared__ __align__(16) u16 As[128 * 32];
    __shared__ __align__(16) u16 Bs[64 * 32];
    const int tm = blockIdx.y * 128, tn = blockIdx.x * 64;
    const int t = threadIdx.x;
    const int lane = t & 63, wave = t >> 6;
    const int wr = wave >> 1, wc = wave & 1;      // wave tile: 64 rows x 32 cols
    const int lq = lane & 15, lg = lane >> 4;
    f32x4 acc[4][2] = {};
    const int srow  = wave * 32 + (lane >> 2);
    const int srowB = wave * 16 + (lane >> 2);
    const int scol = (lane & 3) * 8;
    const u16* ag = A  + (size_t)(tm + srow)  * K + scol;
    const u16* bg = Bt + (size_t)(tn + srowB) * K + scol;
    u16* asl = As + wave * 1024;
    u16* bsl = Bs + wave * 512;
    const size_t rowskip = (size_t)16 * K;
    for (int k0 = 0; k0 < K; k0 += 32) {
        gload_lds16(ag + k0,           asl);
        gload_lds16(ag + k0 + rowskip, asl + 512);
        gload_lds16(bg + k0,           bsl);
        __syncthreads();
        bf16x8 af[4], bfr[2];
        #pragma unroll
        for (int m = 0; m < 4; ++m)
            af[m] = *(const bf16x8*)(As + (wr * 64 + m * 16 + lq) * 32 + lg * 8);
        #pragma unroll
        for (int n = 0; n < 2; ++n)
            bfr[n] = *(const bf16x8*)(Bs + (wc * 32 + n * 16 + lq) * 32 + lg * 8);
        #pragma unroll
        for (int m = 0; m < 4; ++m)
            #pragma unroll
            for (int n = 0; n < 2; ++n)
                acc[m][n] = __builtin_amdgcn_mfma_f32_16x16x32_bf16(af[m], bfr[n], acc[m][n], 0, 0, 0);
        __syncthreads();
    }
    #pragma unroll
    for (int m = 0; m < 4; ++m)
        #pragma unroll
        for (int n = 0; n < 2; ++n) {
            const int col = tn + wc * 32 + n * 16 + lq;
            #pragma unroll
            for (int r = 0; r < 4; ++r) {
                const int row = tm + wr * 64 + m * 16 + lg * 4 + r;
                Cout[(size_t)row * N + col] = acc[m][n][r] + bias[col] + res[(size_t)row * N + col];
            }
        }
}

// ---------------- causal flash attention, KVBLK=64, software-pipelined ---------------
__global__ __launch_bounds__(128, 3) void attn_kernel(
    const u16* __restrict__ qb, const u16* __restrict__ Kp,
    const u16* __restrict__ Vt, u16* __restrict__ o)
{
    const int P = 2048;
    int blk = blockIdx.x;
    int qt = 63 - (blk >> 5);          // heavy tiles dispatched first (LPT)
    int bh = blk & 31;
    int h = bh & 15, b = bh >> 4;
    int w = threadIdx.x >> 6, lane = threadIdx.x & 63;
    int lq = lane & 15, lg = lane >> 4;
    int q0 = qt * 32 + w * 16;
    const u16* qptr = qb + (size_t)(b * P + q0 + lq) * 1024 + h * 64 + lg * 8;
    bf16x8 qf0 = *(const bf16x8*)qptr;
    bf16x8 qf1 = *(const bf16x8*)(qptr + 32);
    const u16* Kbh = Kp + (size_t)bh * P * 64;
    const u16* Vbh = Vt + (size_t)bh * 64 * P;
    const float C2 = 0.03125f * 1.44269504f;     // D^-0.5 * log2(e)
    const int moff = (q0 & 48) + lq;             // causal threshold within last block
    float m2 = -1e30f, l_run = 0.f;
    f32x4 accO[4] = {};
    const int nkvb = (q0 >> 6) + 1;

    bf16x8 kfA[8], kfB[8];
    bf16x4 vf[4][4];

    auto LOADK = [&](bf16x8* kf, int kv0) {
        #pragma unroll
        for (int ss = 0; ss < 4; ++ss) {
            const u16* kp = Kbh + (size_t)(kv0 + ss * 16 + lq) * 64 + lg * 8;
            kf[ss * 2]     = *(const bf16x8*)kp;
            kf[ss * 2 + 1] = *(const bf16x8*)(kp + 32);
        }
    };
    auto LOADV = [&](int kv0) {
        #pragma unroll
        for (int ks = 0; ks < 4; ++ks)
            #pragma unroll
            for (int c = 0; c < 4; ++c)
                vf[ks][c] = *(const bf16x4*)(Vbh + (size_t)(c * 16 + lq) * P + kv0 + ks * 16 + lg * 4);
    };
    auto COMPUTE = [&](const bf16x8* kf, int kv0, bool last) {
        f32x4 st[4];
        #pragma unroll
        for (int ss = 0; ss < 4; ++ss) {
            f32x4 z = {0.f, 0.f, 0.f, 0.f};
            st[ss] = __builtin_amdgcn_mfma_f32_16x16x32_bf16(kf[ss * 2],     qf0, z,      0, 0, 0);
            st[ss] = __builtin_amdgcn_mfma_f32_16x16x32_bf16(kf[ss * 2 + 1], qf1, st[ss], 0, 0, 0);
        }
        float rmax = -1e30f;
        #pragma unroll
        for (int ss = 0; ss < 4; ++ss)
            #pragma unroll
            for (int r = 0; r < 4; ++r) {
                float v = st[ss][r] * C2;
                if (last && (ss * 16 + lg * 4 + r > moff)) v = -1e30f;
                st[ss][r] = v;
                rmax = fmaxf(rmax, v);
            }
        rmax = fmaxf(rmax, __shfl_xor(rmax, 16));
        rmax = fmaxf(rmax, __shfl_xor(rmax, 32));
        if (__any(rmax > m2 + 11.5f)) {            // defer-max (T13)
            float m2n = fmaxf(m2, rmax);
            float alpha = exp2f(m2 - m2n);
            l_run *= alpha;
            #pragma unroll
            for (int r = 0; r < 4; ++r) {
                float ar = __shfl(alpha, lg * 4 + r);
                accO[0][r] *= ar; accO[1][r] *= ar; accO[2][r] *= ar; accO[3][r] *= ar;
            }
            m2 = m2n;
        }
        float psum = 0.f;
        bf16x4 pf[4];
        #pragma unroll
        for (int ss = 0; ss < 4; ++ss)
            #pragma unroll
            for (int r = 0; r < 4; ++r) {
                float pv = exp2f(st[ss][r] - m2);
                psum += pv;
                pf[ss][r] = (short)f2bf(pv);
            }
        psum += __shfl_xor(psum, 16);
        psum += __shfl_xor(psum, 32);
        l_run += psum;
        #pragma unroll
        for (int ks = 0; ks < 4; ++ks)
            #pragma unroll
            for (int c = 0; c < 4; ++c)
                accO[c] = __builtin_amdgcn_mfma_f32_16x16x16bf16_1k(pf[ks], vf[ks][c], accO[c], 0, 0, 0);
    };

    // software pipeline: K double-buffered (issue next-block K at top of iteration),
    // V issued before QK^T so its latency hides under QK^T+softmax.
    LOADK(kfA, 0);
    int kvb = 0;
    while (true) {
        int kv0 = kvb << 6;
        LOADV(kv0);
        if (kvb + 1 < nkvb) LOADK(kfB, kv0 + 64);
        COMPUTE(kfA, kv0, kvb == nkvb - 1);
        if (++kvb >= nkvb) break;
        kv0 = kvb << 6;
        LOADV(kv0);
        if (kvb + 1 < nkvb) LOADK(kfA, kv0 + 64);
        COMPUTE(kfB, kv0, kvb == nkvb - 1);
        if (++kvb >= nkvb) break;
    }

    #pragma unroll
    for (int r = 0; r < 4; ++r) {
        float l_r = __shfl(l_run, lg * 4 + r);
        float inv = 1.0f / l_r;
        size_t orow = (size_t)(b * P + q0 + lg * 4 + r) * 1024 + h * 64;
        #pragma unroll
        for (int c = 0; c < 4; ++c)
            o[orow + c * 16 + lq] = f2bf(accO[c][r] * inv);
    }
}

extern "C" void kernel_launch(void* const* d_in, const int* in_sizes, int n_in,
                              void* d_out, int out_size, void* d_ws, size_t ws_size,
                              hipStream_t stream)
{
    const float* x   = (const float*)d_in[0];
    const float* Wq  = (const float*)d_in[1];
    const float* Wk  = (const float*)d_in[2];
    const float* Wv  = (const float*)d_in[3];
    const float* Wp  = (const float*)d_in[4];
    const float* bp  = (const float*)d_in[5];
    const float* W1  = (const float*)d_in[6];
    const float* b1  = (const float*)d_in[7];
    const float* W2  = (const float*)d_in[8];
    const float* b2  = (const float*)d_in[9];
    const float* g1  = (const float*)d_in[10];
    const float* be1 = (const float*)d_in[11];
    const float* g2  = (const float*)d_in[12];
    const float* be2 = (const float*)d_in[13];

    char* ws = (char*)d_ws;
    u16*  h     = (u16*)(ws + 0);           // 8.39 MB
    u16*  qbuf  = (u16*)(ws + 8388608);     // 8.39 MB
    u16*  Kp    = (u16*)(ws + 16777216);    // 8.39 MB
    u16*  Vt    = (u16*)(ws + 25165824);    // 8.39 MB
    u16*  o     = (u16*)(ws + 33554432);    // 8.39 MB
    float* x1   = (float*)(ws + 41943040);  // 16.78 MB
    u16*  wqkvT = (u16*)(ws + 58720256);    // 6.29 MB
    u16*  wpT   = (u16*)(ws + 65011712);    // 2.10 MB
    u16*  w1T   = (u16*)(ws + 67108864);    // 8.39 MB
    u16*  w2T   = (u16*)(ws + 75497472);    // 8.39 MB -> 80 MB total
    u16*  m     = (u16*)(ws + 0);           // 33.55 MB, aliases h+qbuf+Kp+Vt (dead)
    u16*  h2    = o;                        // aliases o (dead by then)
    float* out  = (float*)d_out;

    transpose_cast_b<<<dim3(2, 32, 16), 256, 0, stream>>>(Wq, wqkvT,           1024, 64, 65536, 65536);
    transpose_cast_b<<<dim3(2, 32, 16), 256, 0, stream>>>(Wk, wqkvT + 1048576, 1024, 64, 65536, 65536);
    transpose_cast_b<<<dim3(2, 32, 16), 256, 0, stream>>>(Wv, wqkvT + 2097152, 1024, 64, 65536, 65536);
    transpose_cast_b<<<dim3(32, 32, 1), 256, 0, stream>>>(Wp, wpT, 1024, 1024, 0, 0);
    transpose_cast_b<<<dim3(128, 32, 1), 256, 0, stream>>>(W1, w1T, 1024, 4096, 0, 0);
    transpose_cast_b<<<dim3(32, 128, 1), 256, 0, stream>>>(W2, w2T, 4096, 1024, 0, 0);

    ln_kernel<<<4096, 256, 0, stream>>>(x, g1, be1, h);
    gemm_bt<3><<<dim3(24, 32), 256, 0, stream>>>(h, wqkvT, 4096, 3072, 1024, nullptr, qbuf, Kp, Vt);
    attn_kernel<<<2048, 128, 0, stream>>>(qbuf, Kp, Vt, o);
    gemm_bt64<<<dim3(16, 32), 256, 0, stream>>>(o, wpT, 4096, 1024, 1024, bp, x, x1);
    ln_kernel<<<4096, 256, 0, stream>>>(x1, g2, be2, h2);
    gemm_bt<2><<<dim3(32, 32), 256, 0, stream>>>(h2, w1T, 4096, 4096, 1024, b1, m, nullptr, nullptr);
    gemm_bt64<<<dim3(16, 32), 256, 0, stream>>>(m, w2T, 4096, 1024, 4096, b2, x1, out);
}

// Round 5
// 290.288 us; speedup vs baseline: 1.5596x; 1.5596x over previous
//
#include <hip/hip_runtime.h>
#include <hip/hip_bf16.h>
#include <stdint.h>

typedef unsigned short u16;
typedef __attribute__((ext_vector_type(4))) float f32x4;
typedef __attribute__((ext_vector_type(8))) short bf16x8;
typedef __attribute__((ext_vector_type(4))) short bf16x4;
typedef __attribute__((ext_vector_type(4))) unsigned short u16x4;

static __device__ __forceinline__ u16 f2bf(float f) {
    union { float f; unsigned u; } v; v.f = f;
    unsigned r = v.u + 0x7fffu + ((v.u >> 16) & 1u);
    return (u16)(r >> 16);
}

// async global->LDS, 16B per lane; LDS dest = wave-uniform base + lane*16
static __device__ __forceinline__ void gload_lds16(const u16* g, u16* l) {
    __builtin_amdgcn_global_load_lds(
        (const __attribute__((address_space(1))) void*)(uintptr_t)g,
        (__attribute__((address_space(3))) void*)(uint32_t)(uintptr_t)l,
        16, 0, 0);
}

// ---------------- weight transpose + cast: out[n*K+k] = (bf16) W[k*N+n] ---------------
__global__ __launch_bounds__(256) void transpose_cast_b(
    const float* __restrict__ W, u16* __restrict__ out,
    int K, int N, long in_bs, long out_bs)
{
    __shared__ float tile[32][33];
    const float* Wb = W + (size_t)blockIdx.z * in_bs;
    u16* ob = out + (size_t)blockIdx.z * out_bs;
    int nt = blockIdx.x * 32, kt = blockIdx.y * 32;
    int tx = threadIdx.x & 31, ty = threadIdx.x >> 5;
    #pragma unroll
    for (int i = ty; i < 32; i += 8)
        tile[i][tx] = Wb[(size_t)(kt + i) * N + nt + tx];
    __syncthreads();
    #pragma unroll
    for (int i = ty; i < 32; i += 8)
        ob[(size_t)(nt + i) * K + kt + tx] = f2bf(tile[tx][i]);
}

// ---------------- layernorm: fp32 in -> bf16 out (D = 1024) ---------------
__global__ __launch_bounds__(256) void ln_kernel(
    const float* __restrict__ x, const float* __restrict__ g,
    const float* __restrict__ be, u16* __restrict__ out)
{
    int row = blockIdx.x;
    int t = threadIdx.x;
    const float4* xr = (const float4*)(x + (size_t)row * 1024);
    float4 v = xr[t];
    float s = v.x + v.y + v.z + v.w;
    float sq = v.x * v.x + v.y * v.y + v.z * v.z + v.w * v.w;
    #pragma unroll
    for (int o = 1; o < 64; o <<= 1) {
        s  += __shfl_xor(s, o);
        sq += __shfl_xor(sq, o);
    }
    __shared__ float ps[4], pq[4];
    if ((t & 63) == 0) { ps[t >> 6] = s; pq[t >> 6] = sq; }
    __syncthreads();
    float S = ps[0] + ps[1] + ps[2] + ps[3];
    float Q = pq[0] + pq[1] + pq[2] + pq[3];
    float mu = S * (1.0f / 1024.0f);
    float var = Q * (1.0f / 1024.0f) - mu * mu;
    float rs = rsqrtf(var + 1e-5f);
    const float4 g4  = ((const float4*)g)[t];
    const float4 be4 = ((const float4*)be)[t];
    u16x4 o4;
    o4[0] = f2bf((v.x - mu) * rs * g4.x + be4.x);
    o4[1] = f2bf((v.y - mu) * rs * g4.y + be4.y);
    o4[2] = f2bf((v.z - mu) * rs * g4.z + be4.z);
    o4[3] = f2bf((v.w - mu) * rs * g4.w + be4.w);
    *(u16x4*)(out + (size_t)row * 1024 + t * 4) = o4;
}

// ---------------- GEMM 128x128: C = A[M,K] * Bt[N,K]^T -------------------------------
// EPI 2: gelu(C + bias[n]) -> bf16 to Cout.
// EPI 3: qkv scatter: col<1024 -> Q [4096][1024] bf16;
//        1024..2047 -> Kf fragment-image; 2048..3071 -> Vf fragment-image.
// Fragment images (per bh, per kv-block of 64, 4096 u16 = 8KB):
//   K elem (p,d): off = (p>>6)*4096 + ((((p&63)>>4)*2 + (d>>5))*64 + ((d>>3)&3)*16 + (p&15))*8 + (d&7)
//   V elem (p,d): off = (p>>6)*4096 + ((((p&63)>>4)*4 + (d>>4))*64 + ((p>>2)&3)*16 + (d&15))*4 + (p&3)
template<int EPI>
__global__ __launch_bounds__(256) void gemm_bt(
    const u16* __restrict__ A, const u16* __restrict__ Bt,
    int M, int N, int K,
    const float* __restrict__ bias,
    void* __restrict__ Cout, u16* __restrict__ Kf, u16* __restrict__ Vf)
{
    __shared__ __align__(16) u16 As[128 * 32];
    __shared__ __align__(16) u16 Bs[128 * 32];
    const int tm = blockIdx.y * 128, tn = blockIdx.x * 128;
    const int t = threadIdx.x;
    const int lane = t & 63, wave = t >> 6;
    const int wr = wave >> 1, wc = wave & 1;
    const int lq = lane & 15, lg = lane >> 4;
    f32x4 acc[4][4] = {};
    const int srow = wave * 32 + (lane >> 2);
    const int scol = (lane & 3) * 8;
    const u16* ag = A  + (size_t)(tm + srow) * K + scol;
    const u16* bg = Bt + (size_t)(tn + srow) * K + scol;
    u16* asl = As + wave * 1024;
    u16* bsl = Bs + wave * 1024;
    const size_t rowskip = (size_t)16 * K;
    for (int k0 = 0; k0 < K; k0 += 32) {
        gload_lds16(ag + k0,           asl);
        gload_lds16(ag + k0 + rowskip, asl + 512);
        gload_lds16(bg + k0,           bsl);
        gload_lds16(bg + k0 + rowskip, bsl + 512);
        __syncthreads();
        bf16x8 af[4], bfr[4];
        #pragma unroll
        for (int m = 0; m < 4; ++m)
            af[m] = *(const bf16x8*)(As + (wr * 64 + m * 16 + lq) * 32 + lg * 8);
        #pragma unroll
        for (int n = 0; n < 4; ++n)
            bfr[n] = *(const bf16x8*)(Bs + (wc * 64 + n * 16 + lq) * 32 + lg * 8);
        #pragma unroll
        for (int m = 0; m < 4; ++m)
            #pragma unroll
            for (int n = 0; n < 4; ++n)
                acc[m][n] = __builtin_amdgcn_mfma_f32_16x16x32_bf16(af[m], bfr[n], acc[m][n], 0, 0, 0);
        __syncthreads();
    }
    #pragma unroll
    for (int n = 0; n < 4; ++n) {
        const int colbase = tn + wc * 64 + n * 16;
        const int col = colbase + lq;
        #pragma unroll
        for (int m = 0; m < 4; ++m) {
            const int row0 = tm + wr * 64 + m * 16 + lg * 4;
            if (EPI == 2) {
                #pragma unroll
                for (int r = 0; r < 4; ++r) {
                    float xx = acc[m][n][r] + bias[col];
                    float ge = 0.5f * xx * (1.0f + erff(xx * 0.70710678118654752f));
                    ((u16*)Cout)[(size_t)(row0 + r) * N + col] = f2bf(ge);
                }
            } else { // EPI == 3
                const int bb = row0 >> 11, pp = row0 & 2047;
                if (colbase < 1024) {
                    #pragma unroll
                    for (int r = 0; r < 4; ++r)
                        ((u16*)Cout)[(size_t)(row0 + r) * 1024 + col] = f2bf(acc[m][n][r]);
                } else if (colbase < 2048) {
                    const int hh = (colbase - 1024) >> 6;
                    const int d = col & 63;
                    u16* kb = Kf + (size_t)(bb * 16 + hh) * 131072 + (pp >> 6) * 4096
                              + ((d >> 5) * 64 + ((d >> 3) & 3) * 16) * 8 + (d & 7);
                    #pragma unroll
                    for (int r = 0; r < 4; ++r) {
                        const int p = pp + r;
                        kb[(((p & 63) >> 4) * 2 * 64 + (p & 15)) * 8] = f2bf(acc[m][n][r]);
                    }
                } else {
                    const int hh = (colbase - 2048) >> 6;
                    const int d = col & 63;
                    u16x4 pk;
                    #pragma unroll
                    for (int r = 0; r < 4; ++r) pk[r] = f2bf(acc[m][n][r]);
                    *(u16x4*)(Vf + (size_t)(bb * 16 + hh) * 131072 + (pp >> 6) * 4096
                              + ((((pp & 63) >> 4) * 4 + (d >> 4)) * 64
                                 + ((pp >> 2) & 3) * 16 + (d & 15)) * 4) = pk;
                }
            }
        }
    }
}

// ---------------- GEMM 128x64 tile (for N=1024 shapes, 2 blocks/CU) ------------------
// out fp32: C + bias[n] + res[m,n]
__global__ __launch_bounds__(256) void gemm_bt64(
    const u16* __restrict__ A, const u16* __restrict__ Bt,
    int M, int N, int K,
    const float* __restrict__ bias, const float* __restrict__ res,
    float* __restrict__ Cout)
{
    __shared__ __align__(16) u16 As[128 * 32];
    __shared__ __align__(16) u16 Bs[64 * 32];
    const int tm = blockIdx.y * 128, tn = blockIdx.x * 64;
    const int t = threadIdx.x;
    const int lane = t & 63, wave = t >> 6;
    const int wr = wave >> 1, wc = wave & 1;      // wave tile: 64 rows x 32 cols
    const int lq = lane & 15, lg = lane >> 4;
    f32x4 acc[4][2] = {};
    const int srow  = wave * 32 + (lane >> 2);
    const int srowB = wave * 16 + (lane >> 2);
    const int scol = (lane & 3) * 8;
    const u16* ag = A  + (size_t)(tm + srow)  * K + scol;
    const u16* bg = Bt + (size_t)(tn + srowB) * K + scol;
    u16* asl = As + wave * 1024;
    u16* bsl = Bs + wave * 512;
    const size_t rowskip = (size_t)16 * K;
    for (int k0 = 0; k0 < K; k0 += 32) {
        gload_lds16(ag + k0,           asl);
        gload_lds16(ag + k0 + rowskip, asl + 512);
        gload_lds16(bg + k0,           bsl);
        __syncthreads();
        bf16x8 af[4], bfr[2];
        #pragma unroll
        for (int m = 0; m < 4; ++m)
            af[m] = *(const bf16x8*)(As + (wr * 64 + m * 16 + lq) * 32 + lg * 8);
        #pragma unroll
        for (int n = 0; n < 2; ++n)
            bfr[n] = *(const bf16x8*)(Bs + (wc * 32 + n * 16 + lq) * 32 + lg * 8);
        #pragma unroll
        for (int m = 0; m < 4; ++m)
            #pragma unroll
            for (int n = 0; n < 2; ++n)
                acc[m][n] = __builtin_amdgcn_mfma_f32_16x16x32_bf16(af[m], bfr[n], acc[m][n], 0, 0, 0);
        __syncthreads();
    }
    #pragma unroll
    for (int m = 0; m < 4; ++m)
        #pragma unroll
        for (int n = 0; n < 2; ++n) {
            const int col = tn + wc * 32 + n * 16 + lq;
            #pragma unroll
            for (int r = 0; r < 4; ++r) {
                const int row = tm + wr * 64 + m * 16 + lg * 4 + r;
                Cout[(size_t)row * N + col] = acc[m][n][r] + bias[col] + res[(size_t)row * N + col];
            }
        }
}

// ---------------- causal flash attention: 4 waves/block, LDS-staged K/V --------------
// Kf/Vf: fragment-ordered images, 4096 u16 per (bh, kv-block of 64).
__global__ __launch_bounds__(256, 4) void attn_kernel(
    const u16* __restrict__ qb, const u16* __restrict__ Kf,
    const u16* __restrict__ Vf, u16* __restrict__ o)
{
    const int P = 2048;
    __shared__ __align__(16) u16 KB[2][4096];
    __shared__ __align__(16) u16 VB[2][4096];
    int blk = blockIdx.x;
    int qt = 31 - (blk >> 5);           // 64-row q tiles, heavy first (LPT)
    int bh = blk & 31;
    int h = bh & 15, b = bh >> 4;
    int w = threadIdx.x >> 6, lane = threadIdx.x & 63;
    int lq = lane & 15, lg = lane >> 4;
    int q0 = qt * 64 + w * 16;
    const u16* qptr = qb + (size_t)(b * P + q0 + lq) * 1024 + h * 64 + lg * 8;
    bf16x8 qf0 = *(const bf16x8*)qptr;
    bf16x8 qf1 = *(const bf16x8*)(qptr + 32);
    const u16* Kfb = Kf + (size_t)bh * 131072;
    const u16* Vfb = Vf + (size_t)bh * 131072;
    const float C2 = 0.03125f * 1.44269504f;     // D^-0.5 * log2(e)
    const int moff = w * 16 + lq;                // causal threshold within last block
    float m2 = -1e30f, l_run = 0.f;
    f32x4 accO[4] = {};
    const int nkvb = qt + 1;

    // wave w stages 4KB: waves 0,1 -> K halves; waves 2,3 -> V halves
    const int vsel = w >> 1, half = w & 1;
    auto STAGE = [&](int buf, int kvb) {
        const u16* src = (vsel ? Vfb : Kfb) + (size_t)kvb * 4096 + half * 2048 + lane * 8;
        u16* dst = (vsel ? &VB[buf][half * 2048] : &KB[buf][half * 2048]);
        #pragma unroll
        for (int i = 0; i < 4; ++i)
            gload_lds16(src + i * 512, dst + i * 512);
    };

    auto COMPUTE = [&](int buf, bool last) {
        const u16* kbase = KB[buf] + lane * 8;
        f32x4 st[4];
        #pragma unroll
        for (int ss = 0; ss < 4; ++ss) {
            bf16x8 kf0 = *(const bf16x8*)(kbase + ss * 1024);
            bf16x8 kf1 = *(const bf16x8*)(kbase + ss * 1024 + 512);
            f32x4 z = {0.f, 0.f, 0.f, 0.f};
            st[ss] = __builtin_amdgcn_mfma_f32_16x16x32_bf16(kf0, qf0, z, 0, 0, 0);
            st[ss] = __builtin_amdgcn_mfma_f32_16x16x32_bf16(kf1, qf1, st[ss], 0, 0, 0);
        }
        float rmax = -1e30f;
        #pragma unroll
        for (int ss = 0; ss < 4; ++ss)
            #pragma unroll
            for (int r = 0; r < 4; ++r) {
                float v = st[ss][r] * C2;
                if (last && (ss * 16 + lg * 4 + r > moff)) v = -1e30f;
                st[ss][r] = v;
                rmax = fmaxf(rmax, v);
            }
        rmax = fmaxf(rmax, __shfl_xor(rmax, 16));
        rmax = fmaxf(rmax, __shfl_xor(rmax, 32));
        if (__any(rmax > m2 + 11.5f)) {            // defer-max (T13)
            float m2n = fmaxf(m2, rmax);
            float alpha = exp2f(m2 - m2n);
            l_run *= alpha;
            #pragma unroll
            for (int r = 0; r < 4; ++r) {
                float ar = __shfl(alpha, lg * 4 + r);
                accO[0][r] *= ar; accO[1][r] *= ar; accO[2][r] *= ar; accO[3][r] *= ar;
            }
            m2 = m2n;
        }
        float psum = 0.f;
        bf16x4 pf[4];
        #pragma unroll
        for (int ss = 0; ss < 4; ++ss)
            #pragma unroll
            for (int r = 0; r < 4; ++r) {
                float pv = exp2f(st[ss][r] - m2);
                psum += pv;
                pf[ss][r] = (short)f2bf(pv);
            }
        psum += __shfl_xor(psum, 16);
        psum += __shfl_xor(psum, 32);
        l_run += psum;
        const u16* vbase = VB[buf] + lane * 4;
        #pragma unroll
        for (int ks = 0; ks < 4; ++ks)
            #pragma unroll
            for (int c = 0; c < 4; ++c) {
                bf16x4 vfr = *(const bf16x4*)(vbase + (ks * 4 + c) * 256);
                accO[c] = __builtin_amdgcn_mfma_f32_16x16x16bf16_1k(pf[ks], vfr, accO[c], 0, 0, 0);
            }
    };

    STAGE(0, 0);
    __syncthreads();
    int cur = 0;
    for (int kvb = 0; kvb < nkvb; ++kvb) {
        if (kvb + 1 < nkvb) STAGE(cur ^ 1, kvb + 1);
        COMPUTE(cur, kvb == nkvb - 1);
        __syncthreads();
        cur ^= 1;
    }

    #pragma unroll
    for (int r = 0; r < 4; ++r) {
        float l_r = __shfl(l_run, lg * 4 + r);
        float inv = 1.0f / l_r;
        size_t orow = (size_t)(b * P + q0 + lg * 4 + r) * 1024 + h * 64;
        #pragma unroll
        for (int c = 0; c < 4; ++c)
            o[orow + c * 16 + lq] = f2bf(accO[c][r] * inv);
    }
}

extern "C" void kernel_launch(void* const* d_in, const int* in_sizes, int n_in,
                              void* d_out, int out_size, void* d_ws, size_t ws_size,
                              hipStream_t stream)
{
    const float* x   = (const float*)d_in[0];
    const float* Wq  = (const float*)d_in[1];
    const float* Wk  = (const float*)d_in[2];
    const float* Wv  = (const float*)d_in[3];
    const float* Wp  = (const float*)d_in[4];
    const float* bp  = (const float*)d_in[5];
    const float* W1  = (const float*)d_in[6];
    const float* b1  = (const float*)d_in[7];
    const float* W2  = (const float*)d_in[8];
    const float* b2  = (const float*)d_in[9];
    const float* g1  = (const float*)d_in[10];
    const float* be1 = (const float*)d_in[11];
    const float* g2  = (const float*)d_in[12];
    const float* be2 = (const float*)d_in[13];

    char* ws = (char*)d_ws;
    u16*  h     = (u16*)(ws + 0);           // 8.39 MB
    u16*  qbuf  = (u16*)(ws + 8388608);     // 8.39 MB
    u16*  Kf    = (u16*)(ws + 16777216);    // 8.39 MB (fragment image)
    u16*  Vf    = (u16*)(ws + 25165824);    // 8.39 MB (fragment image)
    u16*  o     = (u16*)(ws + 33554432);    // 8.39 MB
    float* x1   = (float*)(ws + 41943040);  // 16.78 MB
    u16*  wqkvT = (u16*)(ws + 58720256);    // 6.29 MB
    u16*  wpT   = (u16*)(ws + 65011712);    // 2.10 MB
    u16*  w1T   = (u16*)(ws + 67108864);    // 8.39 MB
    u16*  w2T   = (u16*)(ws + 75497472);    // 8.39 MB -> 80 MB total
    u16*  m     = (u16*)(ws + 0);           // 33.55 MB, aliases h+qbuf+Kf+Vf (dead)
    u16*  h2    = o;                        // aliases o (dead by then)
    float* out  = (float*)d_out;

    transpose_cast_b<<<dim3(2, 32, 16), 256, 0, stream>>>(Wq, wqkvT,           1024, 64, 65536, 65536);
    transpose_cast_b<<<dim3(2, 32, 16), 256, 0, stream>>>(Wk, wqkvT + 1048576, 1024, 64, 65536, 65536);
    transpose_cast_b<<<dim3(2, 32, 16), 256, 0, stream>>>(Wv, wqkvT + 2097152, 1024, 64, 65536, 65536);
    transpose_cast_b<<<dim3(32, 32, 1), 256, 0, stream>>>(Wp, wpT, 1024, 1024, 0, 0);
    transpose_cast_b<<<dim3(128, 32, 1), 256, 0, stream>>>(W1, w1T, 1024, 4096, 0, 0);
    transpose_cast_b<<<dim3(32, 128, 1), 256, 0, stream>>>(W2, w2T, 4096, 1024, 0, 0);

    ln_kernel<<<4096, 256, 0, stream>>>(x, g1, be1, h);
    gemm_bt<3><<<dim3(24, 32), 256, 0, stream>>>(h, wqkvT, 4096, 3072, 1024, nullptr, qbuf, Kf, Vf);
    attn_kernel<<<1024, 256, 0, stream>>>(qbuf, Kf, Vf, o);
    gemm_bt64<<<dim3(16, 32), 256, 0, stream>>>(o, wpT, 4096, 1024, 1024, bp, x, x1);
    ln_kernel<<<4096, 256, 0, stream>>>(x1, g2, be2, h2);
    gemm_bt<2><<<dim3(32, 32), 256, 0, stream>>>(h2, w1T, 4096, 4096, 1024, b1, m, nullptr, nullptr);
    gemm_bt64<<<dim3(16, 32), 256, 0, stream>>>(m, w2T, 4096, 1024, 4096, b2, x1, out);
}